// Round 5
// baseline (411.451 us; speedup 1.0000x reference)
//
#include <hip/hip_runtime.h>
#include <hip/hip_bf16.h>
#include <hip/hip_fp16.h>

typedef _Float16 f16x8 __attribute__((ext_vector_type(8)));
typedef float f32x4 __attribute__((ext_vector_type(4)));
typedef float f32x16 __attribute__((ext_vector_type(16)));

// workspace layout (bytes)
#define OFF_FEAT_T   0u                      // fp32 [B][4096 px][64 ch]  2 MB
#define OFF_FEAT_H   (2u*1024*1024)          // fp16 same                 1 MB
#define OFF_G        (3u*1024*1024)          // fp16 [B][4096][256]       4 MB
#define OFF_WP1      (7u*1024*1024)          // packed fp16 128 KB (32x32 A-frag)
#define OFF_WP2      (OFF_WP1 + 131072u)
#define OFF_WP3      (OFF_WP2 + 131072u)
#define OFF_WP4      (OFF_WP3 + 131072u)     // 16 KB (N padded to 32)
#define OFF_W0PT     (OFF_WP4 + 16384u)      // 288 KB (K=576, 16x16 A-frag for g)

__device__ __forceinline__ unsigned short f2h(float v) {
  return __builtin_bit_cast(unsigned short, (_Float16)v);
}
__device__ __forceinline__ float h2f(unsigned short u) {
  return (float)__builtin_bit_cast(_Float16, u);
}

// ---------------------------------------------------------------- prep ----
// region A: feat [B,C,H,W] -> feat_t fp32 + feat_h fp16, pixel-major
// region B1 (24576): W1..W3 packed as 32x32x16 A-fragments (A = W^T):
//   packed[((kk*8+cb)*64+lane)*8+j] = f16(W[k=kk*16+(lane>>5)*8+j][m=cb*32+(lane&31)])
// region B2 (1024):  W4 padded to 32 out-cols, same 32x32 A-frag layout
// region B3 (18432): W0[:576] (rows reordered k'=tap*64+c) as 16x16x32 A-frags for g_kernel
__global__ __launch_bounds__(256) void prep_kernel(
    const float* __restrict__ feat, const float* __restrict__ W0,
    const float* __restrict__ W1, const float* __restrict__ W2,
    const float* __restrict__ W3, const float* __restrict__ W4,
    char* __restrict__ ws)
{
  int flat = blockIdx.x * 256 + threadIdx.x;
  if (flat < 524288) {
    int c = flat & 63, x = (flat >> 6) & 63, y = (flat >> 12) & 63, b = flat >> 18;
    float f = feat[(((b*64 + c) << 6) + y)*64 + x];
    ((float*)(ws + OFF_FEAT_T))[flat] = f;
    ((unsigned short*)(ws + OFF_FEAT_H))[flat] = f2h(f);
    return;
  }
  int e = flat - 524288;
  if (e >= 44032) return;
  unsigned short o[8];
  char* dst;
  if (e < 24576) {                       // W1,W2,W3 as 32x32 A-frags
    int layer = e >> 13, ee = e & 8191;
    const float* Wsrc = layer == 0 ? W1 : (layer == 1 ? W2 : W3);
    int lane = ee & 63, cb = (ee >> 6) & 7, kk = ee >> 9;
    int m = cb*32 + (lane & 31);
    int k = kk*16 + ((lane >> 5) << 3);
    #pragma unroll
    for (int j = 0; j < 8; ++j) o[j] = f2h(Wsrc[(k + j)*256 + m]);
    dst = ws + OFF_WP1 + layer*131072 + ee*16;
  } else if (e < 25600) {                // W4 [256,3] padded to 32 cols
    int ee = e - 24576;
    int lane = ee & 63, kk = ee >> 6;
    int m = lane & 31;
    int k = kk*16 + ((lane >> 5) << 3);
    #pragma unroll
    for (int j = 0; j < 8; ++j)
      o[j] = (m < 3) ? f2h(W4[(k + j)*3 + m]) : (unsigned short)0;
    dst = ws + OFF_WP4 + ee*16;
  } else {                               // W0[:576] as 16x16 A-frags (for g_kernel)
    int ee = e - 25600;
    int lane = ee & 63, nb = (ee >> 6) & 15, kk = ee >> 10;
    int n = nb*16 + (lane & 15), kb = kk*32 + ((lane >> 4) << 3);
    #pragma unroll
    for (int j = 0; j < 8; ++j) {
      int kp = kb + j, tap = kp >> 6, ch = kp & 63;
      o[j] = f2h(W0[(ch*9 + tap)*256 + n]);
    }
    dst = ws + OFF_W0PT + ee*16;
  }
  uint4 v;
  v.x = (unsigned)o[0] | ((unsigned)o[1] << 16);
  v.y = (unsigned)o[2] | ((unsigned)o[3] << 16);
  v.z = (unsigned)o[4] | ((unsigned)o[5] << 16);
  v.w = (unsigned)o[6] | ((unsigned)o[7] << 16);
  *(uint4*)dst = v;
}

// ------------------------------------------------------------- g table ----
// g[b][p][n] = sum_{k'<576} unfold_tapmajor(feat)[p][k'] * W0[k'][n]   (fp16 out)
// 256 blocks x 512 threads: (b, y, x-half). 32 pixels, 8 waves x 32 out-cols, K=576.
__global__ __launch_bounds__(512) void g_kernel(char* __restrict__ ws)
{
  __shared__ __align__(16) char As[32 * 1152];
  int t = threadIdx.x, lane = t & 63, w = t >> 6;
  int bid = blockIdx.x, b = bid >> 7, rb = bid & 127;
  int y = rb >> 1, x0 = (rb & 1) << 5;
  if (t < 256) {
    int r = t >> 3, cq = t & 7;        // pixel r in [0,32), channel octant
    const unsigned short* fh = (const unsigned short*)(ws + OFF_FEAT_H);
    #pragma unroll
    for (int tap = 0; tap < 9; ++tap) {
      int dy = tap/3 - 1, dx = tap%3 - 1;
      int sy = y + dy, sx = x0 + r + dx;
      uint4 v = {0,0,0,0};
      if (sy >= 0 && sy < 64 && sx >= 0 && sx < 64)
        v = *(const uint4*)(fh + (((((b << 6) + sy) << 6) + sx) << 6) + (cq << 3));
      *(uint4*)(As + r*1152 + ((tap*128 + cq*16) ^ ((r & 7) << 4))) = v;
    }
  }
  __syncthreads();
  const f32x4 vzero = {0.f, 0.f, 0.f, 0.f};
  f32x4 acc[2][2];
  #pragma unroll
  for (int i = 0; i < 2; ++i)
    #pragma unroll
    for (int j = 0; j < 2; ++j) acc[i][j] = vzero;
  const unsigned short* wp0 = (const unsigned short*)(ws + OFF_W0PT);
  int lr = lane & 15, lg = lane >> 4;
  #pragma unroll
  for (int kk = 0; kk < 18; ++kk) {
    f16x8 a[2], bf[2];
    #pragma unroll
    for (int mf = 0; mf < 2; ++mf)
      a[mf] = *(const f16x8*)(wp0 + (((kk*16 + w*2 + mf)*64 + lane) << 3));
    #pragma unroll
    for (int nf = 0; nf < 2; ++nf) {
      int row = nf*16 + lr;
      bf[nf] = *(const f16x8*)(As + row*1152 + ((kk*64 + (lg << 4)) ^ ((row & 7) << 4)));
    }
    #pragma unroll
    for (int mf = 0; mf < 2; ++mf)
      #pragma unroll
      for (int nf = 0; nf < 2; ++nf)
        acc[mf][nf] = __builtin_amdgcn_mfma_f32_16x16x32_f16(a[mf], bf[nf], acc[mf][nf], 0, 0, 0);
  }
  unsigned short* gp = (unsigned short*)(ws + OFF_G);
  #pragma unroll
  for (int mf = 0; mf < 2; ++mf)
    #pragma unroll
    for (int nf = 0; nf < 2; ++nf) {
      int col = (w << 5) + mf*16 + (lg << 2);
      int p = (y << 6) + x0 + nf*16 + lr;
      uint2 ov;
      ov.x = (unsigned)f2h(acc[mf][nf][0]) | ((unsigned)f2h(acc[mf][nf][1]) << 16);
      ov.y = (unsigned)f2h(acc[mf][nf][2]) | ((unsigned)f2h(acc[mf][nf][3]) << 16);
      *(uint2*)(gp + ((((b << 12) + p) << 8) + col)) = ov;
    }
}

// ---------------------------------------------------------- main fused ----
// 32x32x16 MFMA. A = W^T fragments from global, B = activations from LDS.
// 8 waves = 4 col-groups (64 cols) x 2 row-groups (32 rows).
// LDS rows are 512 B = 32 x 16B units, XOR-swizzled: unit' = unit ^ (row & 31).
// D layout (m74/m101): n(batch row)=lane&31, m(out-col)=(reg&3)+8*(reg>>2)+4*(lane>>5).
__device__ __forceinline__ void hidden_layer(const char* src, char* dst,
                                             const unsigned short* wp,
                                             const float* bias,
                                             int lane, int cg, int rg)
{
  f32x16 acc0 = {0.f}, acc1 = {0.f};
  #pragma unroll
  for (int i = 0; i < 16; ++i) { acc0[i] = 0.f; acc1[i] = 0.f; }
  int ln = lane & 31, hi = lane >> 5;
  int row = (rg << 5) + ln;
  const char* srow = src + row*512;
  #pragma unroll
  for (int kk = 0; kk < 16; ++kk) {
    f16x8 a0 = *(const f16x8*)(wp + (((kk*8 + cg*2 + 0)*64 + lane) << 3));
    f16x8 a1 = *(const f16x8*)(wp + (((kk*8 + cg*2 + 1)*64 + lane) << 3));
    f16x8 bb = *(const f16x8*)(srow + ((((kk << 1) + hi) ^ ln) << 4));
    acc0 = __builtin_amdgcn_mfma_f32_32x32x16_f16(a0, bb, acc0, 0, 0, 0);
    acc1 = __builtin_amdgcn_mfma_f32_32x32x16_f16(a1, bb, acc1, 0, 0, 0);
  }
  #pragma unroll
  for (int mf = 0; mf < 2; ++mf) {
    int colbase = (cg << 6) + (mf << 5);
    #pragma unroll
    for (int q = 0; q < 4; ++q) {
      int col0 = colbase + (q << 3) + (hi << 2);
      float4 bv = *(const float4*)(bias + col0);
      float v0 = (mf ? acc1[q*4+0] : acc0[q*4+0]) + bv.x; v0 = v0 > 0.f ? v0 : 0.f;
      float v1 = (mf ? acc1[q*4+1] : acc0[q*4+1]) + bv.y; v1 = v1 > 0.f ? v1 : 0.f;
      float v2 = (mf ? acc1[q*4+2] : acc0[q*4+2]) + bv.z; v2 = v2 > 0.f ? v2 : 0.f;
      float v3 = (mf ? acc1[q*4+3] : acc0[q*4+3]) + bv.w; v3 = v3 > 0.f ? v3 : 0.f;
      uint2 ov;
      ov.x = (unsigned)f2h(v0) | ((unsigned)f2h(v1) << 16);
      ov.y = (unsigned)f2h(v2) | ((unsigned)f2h(v3) << 16);
      int unit = (cg << 3) + (mf << 2) + q;
      *(uint2*)(dst + row*512 + (((unit ^ ln) << 4) + (hi << 3))) = ov;
    }
  }
}

__global__ __launch_bounds__(512, 2) void main_kernel(
    const float* __restrict__ coord, const float* __restrict__ cell,
    const float* __restrict__ W0, const float* __restrict__ b0,
    const float* __restrict__ b1, const float* __restrict__ b2,
    const float* __restrict__ b3, const float* __restrict__ b4,
    const char* __restrict__ ws, float* __restrict__ out)
{
  __shared__ __align__(16) char bufA[64*512];   // reused for fp32 slots [64][76]
  __shared__ __align__(16) char bufB[64*512];
  __shared__ __align__(16) float rel4[64][4];
  __shared__ int prow[64];
  __shared__ float preds[64][4];
  __shared__ float dots[16][12];

  int t = threadIdx.x, lane = t & 63, w = t >> 6;
  int cg = w & 3, rg = w >> 2;
  int bid = blockIdx.x, b = bid >> 12, qt = bid & 4095;
  int qbase = qt << 4;

  if (t < 64) {        // per-row: shift, gather index, rel coords
    int r = t, ql = r >> 2, s = r & 3;
    int gq = (b << 16) + qbase + ql;
    float c0 = coord[gq*2], c1 = coord[gq*2 + 1];
    float ce0 = cell[gq*2], ce1 = cell[gq*2 + 1];
    float vx = (s & 2) ? 1.0f : -1.0f;
    float vy = (s & 1) ? 1.0f : -1.0f;
    float cy = fminf(fmaxf(c0 + vx*(1.0f/64.0f) + 1e-6f, -1.0f + 1e-6f), 1.0f - 1e-6f);
    float cx = fminf(fmaxf(c1 + vy*(1.0f/64.0f) + 1e-6f, -1.0f + 1e-6f), 1.0f - 1e-6f);
    int iy = (int)fminf(fmaxf(rintf((cy + 1.0f)*32.0f - 0.5f), 0.0f), 63.0f);
    int ix = (int)fminf(fmaxf(rintf((cx + 1.0f)*32.0f - 0.5f), 0.0f), 63.0f);
    prow[r] = (iy << 6) + ix;
    float qcy = -1.0f + (float)(2*iy + 1)*(1.0f/64.0f);
    float qcx = -1.0f + (float)(2*ix + 1)*(1.0f/64.0f);
    rel4[r][0] = (c0 - qcy)*64.0f;
    rel4[r][1] = (c1 - qcx)*64.0f;
    rel4[r][2] = ce0*64.0f;
    rel4[r][3] = ce1*64.0f;
  }
  __syncthreads();
  // ---- layer 0: h0 = relu(g[p] + rel.W0[576:580] + b0) -> bufA (fp16, swizzled)
  // row-per-lane; each wave covers 4 of 32 16B-units; coefs via wave-uniform s_loads.
  {
    int r = t & 63;
    int ug = __builtin_amdgcn_readfirstlane(t >> 6);
    float4 rf = *(const float4*)rel4[r];
    const unsigned short* gp = (const unsigned short*)(ws + OFF_G)
                             + (((b << 12) + prow[r]) << 8);
    int rs = r & 31;
    #pragma unroll
    for (int u = 0; u < 4; ++u) {
      int unit = u*8 + ug;                 // 16B unit within the 512B row
      uint4 gv = *(const uint4*)(gp + (unit << 3));
      int cb = unit << 3;
      float c0[8], c1[8], c2[8], c3[8], c4[8];
      #pragma unroll
      for (int j = 0; j < 8; ++j) {
        c0[j] = W0[576*256 + cb + j];
        c1[j] = W0[577*256 + cb + j];
        c2[j] = W0[578*256 + cb + j];
        c3[j] = W0[579*256 + cb + j];
        c4[j] = b0[cb + j];
      }
      unsigned short us[8] = {
        (unsigned short)(gv.x & 0xffff), (unsigned short)(gv.x >> 16),
        (unsigned short)(gv.y & 0xffff), (unsigned short)(gv.y >> 16),
        (unsigned short)(gv.z & 0xffff), (unsigned short)(gv.z >> 16),
        (unsigned short)(gv.w & 0xffff), (unsigned short)(gv.w >> 16) };
      unsigned short ho[8];
      #pragma unroll
      for (int j = 0; j < 8; ++j) {
        float h = h2f(us[j]) + rf.x*c0[j] + rf.y*c1[j]
                + rf.z*c2[j] + rf.w*c3[j] + c4[j];
        h = h > 0.0f ? h : 0.0f;
        ho[j] = f2h(h);
      }
      uint4 ov;
      ov.x = (unsigned)ho[0] | ((unsigned)ho[1] << 16);
      ov.y = (unsigned)ho[2] | ((unsigned)ho[3] << 16);
      ov.z = (unsigned)ho[4] | ((unsigned)ho[5] << 16);
      ov.w = (unsigned)ho[6] | ((unsigned)ho[7] << 16);
      *(uint4*)(bufA + r*512 + ((unit ^ rs) << 4)) = ov;
    }
  }
  __syncthreads();
  hidden_layer(bufA, bufB, (const unsigned short*)(ws + OFF_WP1), b1, lane, cg, rg);
  __syncthreads();
  hidden_layer(bufB, bufA, (const unsigned short*)(ws + OFF_WP2), b2, lane, cg, rg);
  __syncthreads();
  hidden_layer(bufA, bufB, (const unsigned short*)(ws + OFF_WP3), b3, lane, cg, rg);
  __syncthreads();
  if (w < 2) {
    // ---- layer 4: 32x32x16, A = W4^T (cols 0..2 valid of 32). wave w -> rows w*32..+31
    const unsigned short* wp4 = (const unsigned short*)(ws + OFF_WP4);
    f32x16 acc = {0.f};
    #pragma unroll
    for (int i = 0; i < 16; ++i) acc[i] = 0.f;
    int ln = lane & 31, hi = lane >> 5;
    int row = (w << 5) + ln;
    const char* srow = bufB + row*512;
    #pragma unroll
    for (int kk = 0; kk < 16; ++kk) {
      f16x8 a = *(const f16x8*)(wp4 + ((kk*64 + lane) << 3));
      f16x8 bb = *(const f16x8*)(srow + ((((kk << 1) + hi) ^ ln) << 4));
      acc = __builtin_amdgcn_mfma_f32_32x32x16_f16(a, bb, acc, 0, 0, 0);
    }
    if (hi == 0) {     // regs 0..2 hold out-cols 0..2 (q=0, hi=0)
      preds[row][0] = acc[0] + b4[0];
      preds[row][1] = acc[1] + b4[1];
      preds[row][2] = acc[2] + b4[2];
    }
  } else if (w >= 4) {
    // ---- stage fp32 slot vectors into bufA region (stride 76 floats) concurrently
    int tt = t - 256;
    int r = tt >> 2, q4 = tt & 3;
    const float* sp = (const float*)(ws + OFF_FEAT_T)
                    + (((b << 12) + prow[r]) << 6) + (q4 << 4);
    float* Sld = (float*)bufA;
    #pragma unroll
    for (int i = 0; i < 4; ++i)
      *(float4*)(Sld + r*76 + (q4 << 4) + (i << 2)) = *(const float4*)(sp + (i << 2));
  }
  __syncthreads();
  // ---- ensemble: 4 norms + 6 dots per query (fp32 - precision-critical)
  if (t < 160) {
    const int ia[10] = {0,1,2,3, 0,0,0,1,1,2};
    const int ib[10] = {0,1,2,3, 1,2,3,2,3,3};
    int q = t / 10, item = t - q*10;
    const float* Sld = (const float*)bufA;
    const float* ra = Sld + (q*4 + ia[item])*76;
    const float* rb = Sld + (q*4 + ib[item])*76;
    float s = 0.0f;
    #pragma unroll
    for (int i = 0; i < 16; ++i) {
      float4 va = *(const float4*)(ra + (i << 2));
      float4 vb = *(const float4*)(rb + (i << 2));
      s += va.x*vb.x + va.y*vb.y + va.z*vb.z + va.w*vb.w;
    }
    dots[q][item] = s;
  }
  __syncthreads();
  if (t < 16) {
    int q = t;
    float inv[4];
    #pragma unroll
    for (int i = 0; i < 4; ++i) inv[i] = 1.0f / sqrtf(dots[q][i]);
    const int pa[6] = {0,0,0,1,1,2};
    const int pb[6] = {1,2,3,2,3,3};
    float wgt[4] = {0.f, 0.f, 0.f, 0.f};
    #pragma unroll
    for (int pi = 0; pi < 6; ++pi) {
      float cij = dots[q][4 + pi]*inv[pa[pi]]*inv[pb[pi]];
      wgt[pa[pi]] += cij;
      wgt[pb[pi]] += cij;
    }
    float wsum = wgt[0] + wgt[1] + wgt[2] + wgt[3];
    float invw = 1.0f / wsum;
    size_t obase = (size_t)((b << 16) + qbase + q)*3;
    #pragma unroll
    for (int cch = 0; cch < 3; ++cch) {
      float v = preds[q*4 + 0][cch]*wgt[0] + preds[q*4 + 1][cch]*wgt[1]
              + preds[q*4 + 2][cch]*wgt[2] + preds[q*4 + 3][cch]*wgt[3];
      out[obase + cch] = v*invw;
    }
  }
}

extern "C" void kernel_launch(void* const* d_in, const int* in_sizes, int n_in,
                              void* d_out, int out_size, void* d_ws, size_t ws_size,
                              hipStream_t stream) {
  const float* feat  = (const float*)d_in[0];
  const float* coord = (const float*)d_in[1];
  const float* cell  = (const float*)d_in[2];
  const float* W0 = (const float*)d_in[3];
  const float* b0 = (const float*)d_in[4];
  const float* W1 = (const float*)d_in[5];
  const float* b1 = (const float*)d_in[6];
  const float* W2 = (const float*)d_in[7];
  const float* b2 = (const float*)d_in[8];
  const float* W3 = (const float*)d_in[9];
  const float* b3 = (const float*)d_in[10];
  const float* W4 = (const float*)d_in[11];
  const float* b4 = (const float*)d_in[12];
  char* ws = (char*)d_ws;
  float* out = (float*)d_out;
  prep_kernel<<<2220, 256, 0, stream>>>(feat, W0, W1, W2, W3, W4, ws);
  g_kernel<<<256, 512, 0, stream>>>(ws);
  main_kernel<<<8192, 512, 0, stream>>>(coord, cell, W0, b0, b1, b2, b3, b4, ws, out);
}

// Round 7
// 352.664 us; speedup vs baseline: 1.1667x; 1.1667x over previous
//
#include <hip/hip_runtime.h>
#include <hip/hip_bf16.h>
#include <hip/hip_fp16.h>

typedef _Float16 f16x8 __attribute__((ext_vector_type(8)));
typedef float f32x4 __attribute__((ext_vector_type(4)));

// workspace layout (bytes)
#define OFF_FEAT_T   0u                      // fp32 [B][4096 px][64 ch]  2 MB
#define OFF_FEAT_H   (2u*1024*1024)          // fp16 same                 1 MB
#define OFF_G        (3u*1024*1024)          // fp16 [B][4096][256]       4 MB
#define OFF_WP1      (7u*1024*1024)          // packed fp16 128 KB (16x16 A-frag)
#define OFF_WP2      (OFF_WP1 + 131072u)
#define OFF_WP3      (OFF_WP2 + 131072u)
#define OFF_WP4      (OFF_WP3 + 131072u)     // 8 KB (N padded to 16)
#define OFF_W0PT     (OFF_WP4 + 8192u)       // 288 KB (K=576 packed)

__device__ __forceinline__ unsigned short f2h(float v) {
  return __builtin_bit_cast(unsigned short, (_Float16)v);
}
__device__ __forceinline__ float h2f(unsigned short u) {
  return (float)__builtin_bit_cast(_Float16, u);
}
__device__ __forceinline__ unsigned pk2(float a, float b) {
  auto p = __builtin_amdgcn_cvt_pkrtz(a, b);   // v_cvt_pkrtz_f16_f32 (__fp16 x2)
  return __builtin_bit_cast(unsigned, p);
}

// ---------------------------------------------------------------- prep ----
// region A: feat [B,C,H,W] -> feat_t fp32 + feat_h fp16, pixel-major
// region B: pack W1..W4, W0(row-permuted k'=tap*64+c) into MFMA A-fragment layout:
//   packed[((kk*16+nb)*64+lane)*8 + j] = f16(W[k= kk*32+(lane>>4)*8+j][n= nb*16+(lane&15)])
__global__ __launch_bounds__(256) void prep_kernel(
    const float* __restrict__ feat, const float* __restrict__ W0,
    const float* __restrict__ W1, const float* __restrict__ W2,
    const float* __restrict__ W3, const float* __restrict__ W4,
    char* __restrict__ ws)
{
  int flat = blockIdx.x * 256 + threadIdx.x;
  if (flat < 524288) {
    int c = flat & 63, x = (flat >> 6) & 63, y = (flat >> 12) & 63, b = flat >> 18;
    float f = feat[(((b*64 + c) << 6) + y)*64 + x];
    ((float*)(ws + OFF_FEAT_T))[flat] = f;
    ((unsigned short*)(ws + OFF_FEAT_H))[flat] = f2h(f);
    return;
  }
  int e = flat - 524288;
  if (e >= 43520) return;
  unsigned short o[8];
  char* dst;
  if (e < 24576) {                       // W1,W2,W3: K=256,N=256,NB=16 -> 8192 ea
    int layer = e >> 13, ee = e & 8191;
    const float* Wsrc = layer == 0 ? W1 : (layer == 1 ? W2 : W3);
    int lane = ee & 63, nb = (ee >> 6) & 15, kk = ee >> 10;
    int n = nb*16 + (lane & 15), kb = kk*32 + ((lane >> 4) << 3);
    #pragma unroll
    for (int j = 0; j < 8; ++j) o[j] = f2h(Wsrc[(kb + j)*256 + n]);
    dst = ws + OFF_WP1 + layer*131072 + ee*16;
  } else if (e < 25088) {                // W4 [256,3] padded to N=16 -> 512
    int ee = e - 24576;
    int lane = ee & 63, kk = ee >> 6;
    int n = lane & 15, kb = kk*32 + ((lane >> 4) << 3);
    #pragma unroll
    for (int j = 0; j < 8; ++j)
      o[j] = (n < 3) ? f2h(W4[(kb + j)*3 + n]) : (unsigned short)0;
    dst = ws + OFF_WP4 + ee*16;
  } else {                               // W0[:576] rows reordered k'=tap*64+c -> 18432
    int ee = e - 25088;
    int lane = ee & 63, nb = (ee >> 6) & 15, kk = ee >> 10;
    int n = nb*16 + (lane & 15), kb = kk*32 + ((lane >> 4) << 3);
    #pragma unroll
    for (int j = 0; j < 8; ++j) {
      int kp = kb + j, tap = kp >> 6, ch = kp & 63;
      o[j] = f2h(W0[(ch*9 + tap)*256 + n]);
    }
    dst = ws + OFF_W0PT + ee*16;
  }
  uint4 v;
  v.x = (unsigned)o[0] | ((unsigned)o[1] << 16);
  v.y = (unsigned)o[2] | ((unsigned)o[3] << 16);
  v.z = (unsigned)o[4] | ((unsigned)o[5] << 16);
  v.w = (unsigned)o[6] | ((unsigned)o[7] << 16);
  *(uint4*)dst = v;
}

// ------------------------------------------------------------- g table ----
// g[b][p][n] = sum_{k'<576} unfold_tapmajor(feat)[p][k'] * W0[k'][n]   (fp16 out)
// 256 blocks x 256 threads: (b, y, x-half). 32 pixels, 4 waves x 64 out-cols, K=576.
__global__ __launch_bounds__(256) void g_kernel(char* __restrict__ ws)
{
  __shared__ __align__(16) char As[32 * 1152];
  int t = threadIdx.x, lane = t & 63, w = t >> 6;
  int bid = blockIdx.x, b = bid >> 7, rb = bid & 127;
  int y = rb >> 1, x0 = (rb & 1) << 5;
  {
    int r = t >> 3, cq = t & 7;        // pixel r in [0,32), channel octant
    const unsigned short* fh = (const unsigned short*)(ws + OFF_FEAT_H);
    #pragma unroll
    for (int tap = 0; tap < 9; ++tap) {
      int dy = tap/3 - 1, dx = tap%3 - 1;
      int sy = y + dy, sx = x0 + r + dx;
      uint4 v = {0,0,0,0};
      if (sy >= 0 && sy < 64 && sx >= 0 && sx < 64)
        v = *(const uint4*)(fh + (((((b << 6) + sy) << 6) + sx) << 6) + (cq << 3));
      *(uint4*)(As + r*1152 + ((tap*128 + cq*16) ^ ((r & 7) << 4))) = v;
    }
  }
  __syncthreads();
  const f32x4 vzero = {0.f, 0.f, 0.f, 0.f};
  f32x4 acc[4][2];
  #pragma unroll
  for (int i = 0; i < 4; ++i)
    #pragma unroll
    for (int j = 0; j < 2; ++j) acc[i][j] = vzero;
  const unsigned short* wp0 = (const unsigned short*)(ws + OFF_W0PT);
  int lr = lane & 15, lg = lane >> 4;
  #pragma unroll
  for (int kk = 0; kk < 18; ++kk) {
    f16x8 a[4], bf[2];
    #pragma unroll
    for (int mf = 0; mf < 4; ++mf)
      a[mf] = *(const f16x8*)(wp0 + (((kk*16 + w*4 + mf)*64 + lane) << 3));
    #pragma unroll
    for (int nf = 0; nf < 2; ++nf) {
      int row = nf*16 + lr;
      bf[nf] = *(const f16x8*)(As + row*1152 + ((kk*64 + (lg << 4)) ^ ((row & 7) << 4)));
    }
    #pragma unroll
    for (int mf = 0; mf < 4; ++mf)
      #pragma unroll
      for (int nf = 0; nf < 2; ++nf)
        acc[mf][nf] = __builtin_amdgcn_mfma_f32_16x16x32_f16(a[mf], bf[nf], acc[mf][nf], 0, 0, 0);
  }
  unsigned short* gp = (unsigned short*)(ws + OFF_G);
  #pragma unroll
  for (int mf = 0; mf < 4; ++mf)
    #pragma unroll
    for (int nf = 0; nf < 2; ++nf) {
      int col = (w << 6) + mf*16 + (lg << 2);
      int p = (y << 6) + x0 + nf*16 + lr;
      uint2 ov;
      ov.x = pk2(acc[mf][nf][0], acc[mf][nf][1]);
      ov.y = pk2(acc[mf][nf][2], acc[mf][nf][3]);
      *(uint2*)(gp + ((((b << 12) + p) << 8) + col)) = ov;
    }
}

// ---------------------------------------------------------- main fused ----
// A = W^T fragments from global (col-disjoint waves: W read once per block),
// B = activations from LDS. 4 waves; wave wc owns out-cols [wc*64, wc*64+64).
// LDS act rows = 512 B = 32 x 16B units, 5-bit XOR swizzle: unit' = unit ^ (row&31).
__device__ __forceinline__ void hidden_layer(const char* src, char* dst,
                                             const unsigned short* wp,
                                             const float* bias,
                                             int lane, int wc)
{
  const f32x4 vzero = {0.f, 0.f, 0.f, 0.f};
  f32x4 acc[4][4];
  #pragma unroll
  for (int i = 0; i < 4; ++i)
    #pragma unroll
    for (int j = 0; j < 4; ++j) acc[i][j] = vzero;
  int lr = lane & 15, lg = lane >> 4;
  #pragma unroll
  for (int kk = 0; kk < 8; ++kk) {
    f16x8 a[4], bb[4];
    #pragma unroll
    for (int mf = 0; mf < 4; ++mf)
      a[mf] = *(const f16x8*)(wp + (((kk*16 + wc*4 + mf)*64 + lane) << 3));
    #pragma unroll
    for (int nf = 0; nf < 4; ++nf) {
      int row = (nf << 4) + lr;
      bb[nf] = *(const f16x8*)(src + row*512 + ((((kk << 2) + lg) ^ (row & 31)) << 4));
    }
    #pragma unroll
    for (int mf = 0; mf < 4; ++mf)
      #pragma unroll
      for (int nf = 0; nf < 4; ++nf)
        acc[mf][nf] = __builtin_amdgcn_mfma_f32_16x16x32_f16(a[mf], bb[nf], acc[mf][nf], 0, 0, 0);
  }
  #pragma unroll
  for (int mf = 0; mf < 4; ++mf) {
    int col0 = (wc << 6) + (mf << 4) + (lg << 2);
    float4 bv = *(const float4*)(bias + col0);
    int unit = (wc << 3) + (mf << 1) + (lg >> 1);
    int half8 = (lg & 1) << 3;
    #pragma unroll
    for (int nf = 0; nf < 4; ++nf) {
      int row = (nf << 4) + lr;
      float v0 = fmaxf(acc[mf][nf][0] + bv.x, 0.f);
      float v1 = fmaxf(acc[mf][nf][1] + bv.y, 0.f);
      float v2 = fmaxf(acc[mf][nf][2] + bv.z, 0.f);
      float v3 = fmaxf(acc[mf][nf][3] + bv.w, 0.f);
      uint2 ov;
      ov.x = pk2(v0, v1);
      ov.y = pk2(v2, v3);
      *(uint2*)(dst + row*512 + (((unit ^ (row & 31)) << 4) + half8)) = ov;
    }
  }
}

__global__ __launch_bounds__(256) void main_kernel(
    const float* __restrict__ coord, const float* __restrict__ cell,
    const float* __restrict__ W0, const float* __restrict__ b0,
    const float* __restrict__ b1, const float* __restrict__ b2,
    const float* __restrict__ b3, const float* __restrict__ b4,
    const char* __restrict__ ws, float* __restrict__ out)
{
  __shared__ __align__(16) char bufA[64*512];   // reused for fp32 slots [64][76]
  __shared__ __align__(16) char bufB[64*512];
  __shared__ __align__(16) float rel4[64][4];
  __shared__ int prow[64];
  __shared__ float preds[64][4];
  __shared__ float dots[16][12];

  int t = threadIdx.x, lane = t & 63, w = t >> 6;
  int bid = blockIdx.x, b = bid >> 12, qt = bid & 4095;
  int qbase = qt << 4;

  if (t < 64) {        // per-row: shift, gather index, rel coords
    int r = t, ql = r >> 2, s = r & 3;
    int gq = (b << 16) + qbase + ql;
    float c0 = coord[gq*2], c1 = coord[gq*2 + 1];
    float ce0 = cell[gq*2], ce1 = cell[gq*2 + 1];
    float vx = (s & 2) ? 1.0f : -1.0f;
    float vy = (s & 1) ? 1.0f : -1.0f;
    float cy = fminf(fmaxf(c0 + vx*(1.0f/64.0f) + 1e-6f, -1.0f + 1e-6f), 1.0f - 1e-6f);
    float cx = fminf(fmaxf(c1 + vy*(1.0f/64.0f) + 1e-6f, -1.0f + 1e-6f), 1.0f - 1e-6f);
    int iy = (int)fminf(fmaxf(rintf((cy + 1.0f)*32.0f - 0.5f), 0.0f), 63.0f);
    int ix = (int)fminf(fmaxf(rintf((cx + 1.0f)*32.0f - 0.5f), 0.0f), 63.0f);
    prow[r] = (iy << 6) + ix;
    float qcy = -1.0f + (float)(2*iy + 1)*(1.0f/64.0f);
    float qcx = -1.0f + (float)(2*ix + 1)*(1.0f/64.0f);
    rel4[r][0] = (c0 - qcy)*64.0f;
    rel4[r][1] = (c1 - qcx)*64.0f;
    rel4[r][2] = ce0*64.0f;
    rel4[r][3] = ce1*64.0f;
  }
  __syncthreads();
  // ---- layer 0: h0 = relu(g[p] + rel.W0[576:580] + b0) -> bufA (fp16, 5-bit swizzle)
  // row-per-lane; each wave covers 8 of 32 16B-units; coefs via wave-uniform s_loads.
  {
    int r = t & 63;
    int ug = __builtin_amdgcn_readfirstlane(t >> 6);
    float4 rf = *(const float4*)rel4[r];
    const unsigned short* gp = (const unsigned short*)(ws + OFF_G)
                             + (((b << 12) + prow[r]) << 8);
    int rs = r & 31;
    #pragma unroll
    for (int u = 0; u < 8; ++u) {
      int unit = u*4 + ug;                 // 16B unit within the 512B row
      uint4 gv = *(const uint4*)(gp + (unit << 3));
      int cb = unit << 3;
      float c0[8], c1[8], c2[8], c3[8], c4[8];
      #pragma unroll
      for (int j = 0; j < 8; ++j) {
        c0[j] = W0[576*256 + cb + j];
        c1[j] = W0[577*256 + cb + j];
        c2[j] = W0[578*256 + cb + j];
        c3[j] = W0[579*256 + cb + j];
        c4[j] = b0[cb + j];
      }
      unsigned short us[8] = {
        (unsigned short)(gv.x & 0xffff), (unsigned short)(gv.x >> 16),
        (unsigned short)(gv.y & 0xffff), (unsigned short)(gv.y >> 16),
        (unsigned short)(gv.z & 0xffff), (unsigned short)(gv.z >> 16),
        (unsigned short)(gv.w & 0xffff), (unsigned short)(gv.w >> 16) };
      float hv[8];
      #pragma unroll
      for (int j = 0; j < 8; ++j) {
        float h = fmaf(rf.x, c0[j],
                  fmaf(rf.y, c1[j],
                  fmaf(rf.z, c2[j],
                  fmaf(rf.w, c3[j], h2f(us[j]) + c4[j]))));
        hv[j] = fmaxf(h, 0.0f);
      }
      uint4 ov;
      ov.x = pk2(hv[0], hv[1]);
      ov.y = pk2(hv[2], hv[3]);
      ov.z = pk2(hv[4], hv[5]);
      ov.w = pk2(hv[6], hv[7]);
      *(uint4*)(bufA + r*512 + ((unit ^ rs) << 4)) = ov;
    }
  }
  __syncthreads();
  hidden_layer(bufA, bufB, (const unsigned short*)(ws + OFF_WP1), b1, lane, w);
  __syncthreads();
  hidden_layer(bufB, bufA, (const unsigned short*)(ws + OFF_WP2), b2, lane, w);
  __syncthreads();
  hidden_layer(bufA, bufB, (const unsigned short*)(ws + OFF_WP3), b3, lane, w);
  __syncthreads();
  {
    // ---- layer 4 (A = W4^T padded to 16; out-ch in regs, lg==0 lanes valid)
    const unsigned short* wp4 = (const unsigned short*)(ws + OFF_WP4);
    const f32x4 vzero = {0.f, 0.f, 0.f, 0.f};
    f32x4 acc = vzero;
    int lr = lane & 15, lg = lane >> 4;
    int row = (w << 4) + lr;
    #pragma unroll
    for (int kk = 0; kk < 8; ++kk) {
      f16x8 a = *(const f16x8*)(wp4 + ((kk*64 + lane) << 3));
      f16x8 bb = *(const f16x8*)(bufB + row*512 + ((((kk << 2) + lg) ^ (row & 31)) << 4));
      acc = __builtin_amdgcn_mfma_f32_16x16x32_f16(a, bb, acc, 0, 0, 0);
    }
    if (lg == 0) {
      #pragma unroll
      for (int ch = 0; ch < 3; ++ch) preds[row][ch] = acc[ch] + b4[ch];
    }
  }
  // ---- stage fp32 slot vectors into bufA region (stride 76 floats)
  {
    int r = t >> 2, q4 = t & 3;
    const float* sp = (const float*)(ws + OFF_FEAT_T)
                    + (((b << 12) + prow[r]) << 6) + (q4 << 4);
    float* Sld = (float*)bufA;
    #pragma unroll
    for (int i = 0; i < 4; ++i)
      *(float4*)(Sld + r*76 + (q4 << 4) + (i << 2)) = *(const float4*)(sp + (i << 2));
  }
  __syncthreads();
  // ---- ensemble: 4 norms + 6 dots per query (fp32 - precision-critical)
  if (t < 160) {
    const int ia[10] = {0,1,2,3, 0,0,0,1,1,2};
    const int ib[10] = {0,1,2,3, 1,2,3,2,3,3};
    int q = t / 10, item = t - q*10;
    const float* Sld = (const float*)bufA;
    const float* ra = Sld + (q*4 + ia[item])*76;
    const float* rb = Sld + (q*4 + ib[item])*76;
    float s = 0.0f;
    #pragma unroll
    for (int i = 0; i < 16; ++i) {
      float4 va = *(const float4*)(ra + (i << 2));
      float4 vb = *(const float4*)(rb + (i << 2));
      s += va.x*vb.x + va.y*vb.y + va.z*vb.z + va.w*vb.w;
    }
    dots[q][item] = s;
  }
  __syncthreads();
  if (t < 16) {
    int q = t;
    float inv[4];
    #pragma unroll
    for (int i = 0; i < 4; ++i) inv[i] = 1.0f / sqrtf(dots[q][i]);
    const int pa[6] = {0,0,0,1,1,2};
    const int pb[6] = {1,2,3,2,3,3};
    float wgt[4] = {0.f, 0.f, 0.f, 0.f};
    #pragma unroll
    for (int pi = 0; pi < 6; ++pi) {
      float cij = dots[q][4 + pi]*inv[pa[pi]]*inv[pb[pi]];
      wgt[pa[pi]] += cij;
      wgt[pb[pi]] += cij;
    }
    float wsum = wgt[0] + wgt[1] + wgt[2] + wgt[3];
    float invw = 1.0f / wsum;
    size_t obase = (size_t)((b << 16) + qbase + q)*3;
    #pragma unroll
    for (int cch = 0; cch < 3; ++cch) {
      float v = preds[q*4 + 0][cch]*wgt[0] + preds[q*4 + 1][cch]*wgt[1]
              + preds[q*4 + 2][cch]*wgt[2] + preds[q*4 + 3][cch]*wgt[3];
      out[obase + cch] = v*invw;
    }
  }
}

extern "C" void kernel_launch(void* const* d_in, const int* in_sizes, int n_in,
                              void* d_out, int out_size, void* d_ws, size_t ws_size,
                              hipStream_t stream) {
  const float* feat  = (const float*)d_in[0];
  const float* coord = (const float*)d_in[1];
  const float* cell  = (const float*)d_in[2];
  const float* W0 = (const float*)d_in[3];
  const float* b0 = (const float*)d_in[4];
  const float* W1 = (const float*)d_in[5];
  const float* b1 = (const float*)d_in[6];
  const float* W2 = (const float*)d_in[7];
  const float* b2 = (const float*)d_in[8];
  const float* W3 = (const float*)d_in[9];
  const float* b3 = (const float*)d_in[10];
  const float* W4 = (const float*)d_in[11];
  const float* b4 = (const float*)d_in[12];
  char* ws = (char*)d_ws;
  float* out = (float*)d_out;
  prep_kernel<<<2218, 256, 0, stream>>>(feat, W0, W1, W2, W3, W4, ws);
  g_kernel<<<256, 256, 0, stream>>>(ws);
  main_kernel<<<8192, 256, 0, stream>>>(coord, cell, W0, b0, b1, b2, b3, b4, ws, out);
}